// Round 1
// baseline (1652.862 us; speedup 1.0000x reference)
//
#include <hip/hip_runtime.h>
#include <hip/hip_bf16.h>

// FeatureInspector: ska (dynamic 3x3 per-group aggregation) -> *roi ->
// grouped conv3x3(G=8)+BN+ReLU -> conv1x1+BN -> out = ska + y
//
// Shapes: x (8,256,128,128) f32; dw (8,8,9,128,128); roi (8,1,128,128)
// w1 (256,32,3,3) groups=8; w2 (256,256,1,1); bn params (256,)
//
// ws layout (bytes):
//   [0, 134217728)              y0 = ska*roi
//   [134217728, 268435456)      h1 = relu(bn1(conv1(y0)))
//   [268435456, 268730368)      w1t packed [g][ci*9+k][co]  (73728 f)
//   [268730368, 268992512)      w2t4 packed [ci4][co] float4 (16384 f4)

#define HW 16384
#define EPS 1e-5f

__global__ __launch_bounds__(256) void prepack_w1(const float* __restrict__ w1,
                                                  float* __restrict__ w1t) {
  int o = blockIdx.x * 256 + threadIdx.x;      // 73728 total = 288 blocks
  int co  = o & 31;
  int rem = (o >> 5) % 288;                    // ci*9+k
  int g   = (o >> 5) / 288;
  w1t[o] = w1[(g * 32 + co) * 288 + rem];
}

__global__ __launch_bounds__(256) void prepack_w2(const float* __restrict__ w2,
                                                  float* __restrict__ w2t4) {
  int o = blockIdx.x * 256 + threadIdx.x;      // 16384 float4s = 64 blocks
  int co  = o & 255;
  int ci4 = o >> 8;
  const float4 v = *(const float4*)&w2[co * 256 + ci4 * 4];
  *(float4*)&w2t4[(size_t)o * 4] = v;
}

// One thread per output element: ska -> d_out, ska*roi -> y0(ws)
__global__ __launch_bounds__(256) void ska_kernel(const float* __restrict__ x,
                                                  const float* __restrict__ dw,
                                                  const float* __restrict__ roi,
                                                  float* __restrict__ out,
                                                  float* __restrict__ y0) {
  int idx = blockIdx.x * 256 + threadIdx.x;    // flat over (b,c,h,w)
  int w = idx & 127;
  int h = (idx >> 7) & 127;
  int c = (idx >> 14) & 255;
  int b = idx >> 22;
  int g = c >> 5;

  const float* dwb = dw + ((size_t)(b * 8 + g) * 9) * HW + h * 128 + w;
  float s = 0.f;
#pragma unroll
  for (int kh = 0; kh < 3; ++kh) {
    int hh = h + kh - 1;
    if ((unsigned)hh >= 128u) continue;
#pragma unroll
    for (int kw = 0; kw < 3; ++kw) {
      int ww = w + kw - 1;
      if ((unsigned)ww >= 128u) continue;
      float xv = x[idx + (kh - 1) * 128 + (kw - 1)];
      float wv = dwb[(kh * 3 + kw) * HW];
      s += xv * wv;
    }
  }
  out[idx] = s;
  y0[idx]  = s * roi[b * HW + h * 128 + w];
}

// Grouped conv3x3 + BN1 + ReLU. Block: 256 thr = 16x16 pixel tile of one
// (b, g). Each thread accumulates all 32 co of the group. x-tile staged in
// LDS in two ci-phases of 16 channels (keeps static LDS < 64 KB).
__global__ __launch_bounds__(256) void conv1_kernel(
    const float* __restrict__ y0, const float* __restrict__ w1t,
    const float* __restrict__ g1, const float* __restrict__ b1,
    const float* __restrict__ m1, const float* __restrict__ v1,
    float* __restrict__ h1out) {
  __shared__ float lds_x[16 * 324];   // 16 ci x 18 x 18 = 20736 B
  __shared__ float lds_w[9216];       // [ci*9+k][co]      = 36864 B

  int blk  = blockIdx.x;              // 4096 = 8b * 8g * 64 tiles
  int tile = blk & 63;
  int g    = (blk >> 6) & 7;
  int b    = blk >> 9;
  int h0   = (tile >> 3) * 16;
  int w0   = (tile & 7) * 16;
  int tid  = threadIdx.x;
  int tx = tid & 15, ty = tid >> 4;

  const float* wsrc = w1t + g * 9216;
  for (int j = tid; j < 9216; j += 256) lds_w[j] = wsrc[j];

  const float* xsrc = y0 + ((size_t)(b * 256 + g * 32)) * HW;

  float acc[32];
#pragma unroll
  for (int i = 0; i < 32; ++i) acc[i] = 0.f;

  for (int half = 0; half < 2; ++half) {
    __syncthreads();                  // lds_x reuse safe (also covers w load)
    for (int j = tid; j < 16 * 324; j += 256) {
      int cil = j / 324;
      int r   = j - cil * 324;
      int yy  = r / 18;
      int xx  = r - yy * 18;
      int gh = h0 - 1 + yy, gw = w0 - 1 + xx;
      float v = 0.f;
      if ((unsigned)gh < 128u && (unsigned)gw < 128u)
        v = xsrc[(half * 16 + cil) * HW + gh * 128 + gw];
      lds_x[j] = v;
    }
    __syncthreads();

    for (int cil = 0; cil < 16; ++cil) {
      int ci = half * 16 + cil;
      float xv[9];
      const float* xb = &lds_x[cil * 324 + ty * 18 + tx];
#pragma unroll
      for (int kh = 0; kh < 3; ++kh)
#pragma unroll
        for (int kw = 0; kw < 3; ++kw) xv[kh * 3 + kw] = xb[kh * 18 + kw];
      const float* wb = &lds_w[ci * 9 * 32];
#pragma unroll
      for (int k = 0; k < 9; ++k) {
        float xk = xv[k];
#pragma unroll
        for (int co4 = 0; co4 < 8; ++co4) {
          const float4 w4 = *(const float4*)&wb[k * 32 + co4 * 4];
          acc[co4 * 4 + 0] += xk * w4.x;
          acc[co4 * 4 + 1] += xk * w4.y;
          acc[co4 * 4 + 2] += xk * w4.z;
          acc[co4 * 4 + 3] += xk * w4.w;
        }
      }
    }
  }

  size_t obase = ((size_t)(b * 256 + g * 32)) * HW + (h0 + ty) * 128 + (w0 + tx);
#pragma unroll
  for (int co = 0; co < 32; ++co) {
    int c = g * 32 + co;
    float inv  = g1[c] * rsqrtf(v1[c] + EPS);
    float bias = b1[c] - m1[c] * inv;
    float r = acc[co] * inv + bias;
    h1out[obase + (size_t)co * HW] = fmaxf(r, 0.f);
  }
}

// 1x1 conv (K=256 matvec per pixel) + BN2 + residual add of ska (in d_out).
// Block: 256 thr, co = lane, 32-pixel tile in LDS, weights streamed (L2).
__global__ __launch_bounds__(256) void conv2_kernel(
    const float* __restrict__ h1, const float* __restrict__ w2t4,
    const float* __restrict__ g2, const float* __restrict__ b2,
    const float* __restrict__ m2, const float* __restrict__ v2,
    float* __restrict__ out) {
  __shared__ float lds_h[256 * 32];   // [ci][p] = 32 KB

  int blk = blockIdx.x;               // 4096 = 8b * 512 tiles
  int b   = blk >> 9;
  int p0  = (blk & 511) * 32;
  int tid = threadIdx.x;

  for (int j = tid; j < 2048; j += 256) {
    int ci = j >> 3, p4 = j & 7;
    const float4 v =
        *(const float4*)&h1[((size_t)(b * 256 + ci)) * HW + p0 + p4 * 4];
    *(float4*)&lds_h[ci * 32 + p4 * 4] = v;
  }
  __syncthreads();

  int co = tid;
  float acc[32];
#pragma unroll
  for (int i = 0; i < 32; ++i) acc[i] = 0.f;

  const float4* wv = (const float4*)w2t4;   // [ci4*256 + co]
  for (int ci4 = 0; ci4 < 64; ++ci4) {
    float4 w4 = wv[ci4 * 256 + co];
#pragma unroll
    for (int jj = 0; jj < 4; ++jj) {
      float wj = (jj == 0) ? w4.x : (jj == 1) ? w4.y : (jj == 2) ? w4.z : w4.w;
      const float* hb = &lds_h[(ci4 * 4 + jj) * 32];
#pragma unroll
      for (int pq = 0; pq < 8; ++pq) {
        const float4 hv = *(const float4*)&hb[pq * 4];
        acc[pq * 4 + 0] += wj * hv.x;
        acc[pq * 4 + 1] += wj * hv.y;
        acc[pq * 4 + 2] += wj * hv.z;
        acc[pq * 4 + 3] += wj * hv.w;
      }
    }
  }

  float inv  = g2[co] * rsqrtf(v2[co] + EPS);
  float bias = b2[co] - m2[co] * inv;
  float* ob = out + ((size_t)(b * 256 + co)) * HW + p0;
#pragma unroll
  for (int pq = 0; pq < 8; ++pq) {
    float4 s = *(float4*)&ob[pq * 4];
    s.x += acc[pq * 4 + 0] * inv + bias;
    s.y += acc[pq * 4 + 1] * inv + bias;
    s.z += acc[pq * 4 + 2] * inv + bias;
    s.w += acc[pq * 4 + 3] * inv + bias;
    *(float4*)&ob[pq * 4] = s;
  }
}

extern "C" void kernel_launch(void* const* d_in, const int* in_sizes, int n_in,
                              void* d_out, int out_size, void* d_ws,
                              size_t ws_size, hipStream_t stream) {
  const float* x   = (const float*)d_in[0];
  const float* dw  = (const float*)d_in[1];
  const float* roi = (const float*)d_in[2];
  const float* w1  = (const float*)d_in[3];
  const float* g1  = (const float*)d_in[4];
  const float* b1  = (const float*)d_in[5];
  const float* m1  = (const float*)d_in[6];
  const float* v1  = (const float*)d_in[7];
  const float* w2  = (const float*)d_in[8];
  const float* g2  = (const float*)d_in[9];
  const float* b2  = (const float*)d_in[10];
  const float* m2  = (const float*)d_in[11];
  const float* v2  = (const float*)d_in[12];
  float* out = (float*)d_out;

  char* ws = (char*)d_ws;
  float* y0   = (float*)ws;                           // 134217728 B
  float* h1   = (float*)(ws + 134217728);             // 134217728 B
  float* w1t  = (float*)(ws + 268435456);             // 294912 B
  float* w2t4 = (float*)(ws + 268435456 + 294912);    // 262144 B

  prepack_w1<<<288, 256, 0, stream>>>(w1, w1t);
  prepack_w2<<<64, 256, 0, stream>>>(w2, w2t4);
  ska_kernel<<<131072, 256, 0, stream>>>(x, dw, roi, out, y0);
  conv1_kernel<<<4096, 256, 0, stream>>>(y0, w1t, g1, b1, m1, v1, h1);
  conv2_kernel<<<4096, 256, 0, stream>>>(h1, w2t4, g2, b2, m2, v2, out);
}

// Round 2
// 1205.866 us; speedup vs baseline: 1.3707x; 1.3707x over previous
//
#include <hip/hip_runtime.h>
#include <hip/hip_bf16.h>

// FeatureInspector: ska (dynamic 3x3 per-group aggregation) -> *roi ->
// grouped conv3x3(G=8)+BN+ReLU -> conv1x1+BN -> out = ska + y
//
// R1: register-blocked convs (4co x 8px per thread) so LDS reads amortize
// over 32 FMAs; conv1 weights staged per-half (LDS 39 KB -> 4 blocks/CU);
// conv2 h-reads wave-uniform (broadcast, conflict-free), weights from L2.
//
// ws layout (bytes):
//   [0, 134217728)              y0 = ska*roi
//   [134217728, 268435456)      h1 = relu(bn1(conv1(y0)))
//   [268435456, 268730368)      w1t packed [g][ci*9+k][co]  (73728 f)
//   [268730368, 268992512)      w2t packed [ci][co]         (65536 f)

#define HW 16384
#define EPS 1e-5f

__global__ __launch_bounds__(256) void prepack_w1(const float* __restrict__ w1,
                                                  float* __restrict__ w1t) {
  int o = blockIdx.x * 256 + threadIdx.x;      // 73728 total = 288 blocks
  int co  = o & 31;
  int rem = (o >> 5) % 288;                    // ci*9+k
  int g   = (o >> 5) / 288;
  w1t[o] = w1[(g * 32 + co) * 288 + rem];
}

__global__ __launch_bounds__(256) void prepack_w2(const float* __restrict__ w2,
                                                  float* __restrict__ w2t) {
  int o = blockIdx.x * 256 + threadIdx.x;      // 65536 = 256 blocks
  int co = o & 255;
  int ci = o >> 8;
  w2t[o] = w2[co * 256 + ci];                  // [ci][co]
}

// One thread per output element: ska -> d_out, ska*roi -> y0(ws)
__global__ __launch_bounds__(256) void ska_kernel(const float* __restrict__ x,
                                                  const float* __restrict__ dw,
                                                  const float* __restrict__ roi,
                                                  float* __restrict__ out,
                                                  float* __restrict__ y0) {
  int idx = blockIdx.x * 256 + threadIdx.x;    // flat over (b,c,h,w)
  int w = idx & 127;
  int h = (idx >> 7) & 127;
  int c = (idx >> 14) & 255;
  int b = idx >> 22;
  int g = c >> 5;

  const float* dwb = dw + ((size_t)(b * 8 + g) * 9) * HW + h * 128 + w;
  float s = 0.f;
#pragma unroll
  for (int kh = 0; kh < 3; ++kh) {
    int hh = h + kh - 1;
    if ((unsigned)hh >= 128u) continue;
#pragma unroll
    for (int kw = 0; kw < 3; ++kw) {
      int ww = w + kw - 1;
      if ((unsigned)ww >= 128u) continue;
      float xv = x[idx + (kh - 1) * 128 + (kw - 1)];
      float wv = dwb[(kh * 3 + kw) * HW];
      s += xv * wv;
    }
  }
  out[idx] = s;
  y0[idx]  = s * roi[b * HW + h * 128 + w];
}

// Grouped conv3x3 + BN1 + ReLU. Block: 256 thr = 16x16 pixel tile of one
// (b, g). Thread: 4 co x 8 px (half-row). x and w staged in LDS in two
// ci-phases of 16 channels. LDS = 20736 + 18432 = 39168 B -> 4 blocks/CU.
__global__ __launch_bounds__(256) void conv1_kernel(
    const float* __restrict__ y0, const float* __restrict__ w1t,
    const float* __restrict__ g1, const float* __restrict__ b1,
    const float* __restrict__ m1, const float* __restrict__ v1,
    float* __restrict__ h1out) {
  __shared__ float lds_x[16 * 324];   // 16 ci x 18 x 18
  __shared__ float lds_w[16 * 288];   // 16 ci x 9 k x 32 co (one half)

  int blk  = blockIdx.x;              // 4096 = 8b * 8g * 64 tiles
  int tile = blk & 63;
  int g    = (blk >> 6) & 7;
  int b    = blk >> 9;
  int h0   = (tile >> 3) * 16;
  int w0   = (tile & 7) * 16;
  int tid  = threadIdx.x;
  int cg   = tid >> 5;                // co-group: co = cg*4 .. cg*4+3
  int p    = tid & 31;                // pixel position
  int row  = p >> 1;                  // 0..15
  int colb = (p & 1) * 8;             // 0 or 8

  const float* xsrc = y0 + ((size_t)(b * 256 + g * 32)) * HW;
  const float* wsrc = w1t + g * 9216;

  float acc[32];                      // [cc][px]
#pragma unroll
  for (int i = 0; i < 32; ++i) acc[i] = 0.f;

  for (int half = 0; half < 2; ++half) {
    __syncthreads();
    for (int j = tid; j < 16 * 324; j += 256) {
      int cil = j / 324;
      int r   = j - cil * 324;
      int yy  = r / 18;
      int xx  = r - yy * 18;
      int gh = h0 - 1 + yy, gw = w0 - 1 + xx;
      float v = 0.f;
      if ((unsigned)gh < 128u && (unsigned)gw < 128u)
        v = xsrc[(half * 16 + cil) * HW + gh * 128 + gw];
      lds_x[j] = v;
    }
    for (int j = tid; j < 16 * 288; j += 256)
      lds_w[j] = wsrc[half * 4608 + j];
    __syncthreads();

    for (int cil = 0; cil < 16; ++cil) {
      float xr[3][10];
      const float* xb = &lds_x[cil * 324 + row * 18 + colb];
#pragma unroll
      for (int dr = 0; dr < 3; ++dr)
#pragma unroll
        for (int dc = 0; dc < 10; ++dc) xr[dr][dc] = xb[dr * 18 + dc];

      const float* wb = &lds_w[cil * 288 + cg * 4];
#pragma unroll
      for (int k = 0; k < 9; ++k) {
        const float4 w4 = *(const float4*)&wb[k * 32];
        int kh = k / 3, kw = k % 3;
#pragma unroll
        for (int px = 0; px < 8; ++px) {
          float xv = xr[kh][px + kw];
          acc[0 * 8 + px] += xv * w4.x;
          acc[1 * 8 + px] += xv * w4.y;
          acc[2 * 8 + px] += xv * w4.z;
          acc[3 * 8 + px] += xv * w4.w;
        }
      }
    }
  }

#pragma unroll
  for (int cc = 0; cc < 4; ++cc) {
    int c = g * 32 + cg * 4 + cc;
    float inv  = g1[c] * rsqrtf(v1[c] + EPS);
    float bias = b1[c] - m1[c] * inv;
    float* ob = h1out + ((size_t)(b * 256 + c)) * HW + (h0 + row) * 128 +
                w0 + colb;
    float4 r0, r1;
    r0.x = fmaxf(acc[cc * 8 + 0] * inv + bias, 0.f);
    r0.y = fmaxf(acc[cc * 8 + 1] * inv + bias, 0.f);
    r0.z = fmaxf(acc[cc * 8 + 2] * inv + bias, 0.f);
    r0.w = fmaxf(acc[cc * 8 + 3] * inv + bias, 0.f);
    r1.x = fmaxf(acc[cc * 8 + 4] * inv + bias, 0.f);
    r1.y = fmaxf(acc[cc * 8 + 5] * inv + bias, 0.f);
    r1.z = fmaxf(acc[cc * 8 + 6] * inv + bias, 0.f);
    r1.w = fmaxf(acc[cc * 8 + 7] * inv + bias, 0.f);
    *(float4*)&ob[0] = r0;
    *(float4*)&ob[4] = r1;
  }
}

// 1x1 conv (K=256) + BN2 + residual add of ska (in d_out).
// Block: 256 thr, tile = 32 px of one b; outputs 256co x 32px.
// Thread: 4 co x 8 px. h-reads wave-uniform (broadcast); w from L2 coalesced.
__global__ __launch_bounds__(256) void conv2_kernel(
    const float* __restrict__ h1, const float* __restrict__ w2t,
    const float* __restrict__ g2, const float* __restrict__ b2,
    const float* __restrict__ m2, const float* __restrict__ v2,
    float* __restrict__ out) {
  __shared__ float lds_h[256 * 32];   // [ci][p] = 32 KB

  int blk = blockIdx.x;               // 4096 = 8b * 512 tiles
  int b   = blk >> 9;
  int p0  = (blk & 511) * 32;
  int tid = threadIdx.x;
  int co4 = tid & 63;                 // co = co4*4 .. co4*4+3
  int pq  = tid >> 6;                 // px = pq*8 .. pq*8+7

  for (int j = tid; j < 2048; j += 256) {
    int ci = j >> 3, p4 = j & 7;
    const float4 v =
        *(const float4*)&h1[((size_t)(b * 256 + ci)) * HW + p0 + p4 * 4];
    *(float4*)&lds_h[ci * 32 + p4 * 4] = v;
  }
  __syncthreads();

  float acc[32];                      // [cc][px]
#pragma unroll
  for (int i = 0; i < 32; ++i) acc[i] = 0.f;

#pragma unroll 4
  for (int ci = 0; ci < 256; ++ci) {
    const float4 w4 = *(const float4*)&w2t[ci * 256 + co4 * 4];
    const float* hb = &lds_h[ci * 32 + pq * 8];
    const float4 h0 = *(const float4*)&hb[0];
    const float4 h1v = *(const float4*)&hb[4];
    acc[0]  += w4.x * h0.x;  acc[1]  += w4.x * h0.y;
    acc[2]  += w4.x * h0.z;  acc[3]  += w4.x * h0.w;
    acc[4]  += w4.x * h1v.x; acc[5]  += w4.x * h1v.y;
    acc[6]  += w4.x * h1v.z; acc[7]  += w4.x * h1v.w;
    acc[8]  += w4.y * h0.x;  acc[9]  += w4.y * h0.y;
    acc[10] += w4.y * h0.z;  acc[11] += w4.y * h0.w;
    acc[12] += w4.y * h1v.x; acc[13] += w4.y * h1v.y;
    acc[14] += w4.y * h1v.z; acc[15] += w4.y * h1v.w;
    acc[16] += w4.z * h0.x;  acc[17] += w4.z * h0.y;
    acc[18] += w4.z * h0.z;  acc[19] += w4.z * h0.w;
    acc[20] += w4.z * h1v.x; acc[21] += w4.z * h1v.y;
    acc[22] += w4.z * h1v.z; acc[23] += w4.z * h1v.w;
    acc[24] += w4.w * h0.x;  acc[25] += w4.w * h0.y;
    acc[26] += w4.w * h0.z;  acc[27] += w4.w * h0.w;
    acc[28] += w4.w * h1v.x; acc[29] += w4.w * h1v.y;
    acc[30] += w4.w * h1v.z; acc[31] += w4.w * h1v.w;
  }

#pragma unroll
  for (int cc = 0; cc < 4; ++cc) {
    int co = co4 * 4 + cc;
    float inv  = g2[co] * rsqrtf(v2[co] + EPS);
    float bias = b2[co] - m2[co] * inv;
    float* ob = out + ((size_t)(b * 256 + co)) * HW + p0 + pq * 8;
    float4 s0 = *(float4*)&ob[0];
    float4 s1 = *(float4*)&ob[4];
    s0.x += acc[cc * 8 + 0] * inv + bias;
    s0.y += acc[cc * 8 + 1] * inv + bias;
    s0.z += acc[cc * 8 + 2] * inv + bias;
    s0.w += acc[cc * 8 + 3] * inv + bias;
    s1.x += acc[cc * 8 + 4] * inv + bias;
    s1.y += acc[cc * 8 + 5] * inv + bias;
    s1.z += acc[cc * 8 + 6] * inv + bias;
    s1.w += acc[cc * 8 + 7] * inv + bias;
    *(float4*)&ob[0] = s0;
    *(float4*)&ob[4] = s1;
  }
}

extern "C" void kernel_launch(void* const* d_in, const int* in_sizes, int n_in,
                              void* d_out, int out_size, void* d_ws,
                              size_t ws_size, hipStream_t stream) {
  const float* x   = (const float*)d_in[0];
  const float* dw  = (const float*)d_in[1];
  const float* roi = (const float*)d_in[2];
  const float* w1  = (const float*)d_in[3];
  const float* g1  = (const float*)d_in[4];
  const float* b1  = (const float*)d_in[5];
  const float* m1  = (const float*)d_in[6];
  const float* v1  = (const float*)d_in[7];
  const float* w2  = (const float*)d_in[8];
  const float* g2  = (const float*)d_in[9];
  const float* b2  = (const float*)d_in[10];
  const float* m2  = (const float*)d_in[11];
  const float* v2  = (const float*)d_in[12];
  float* out = (float*)d_out;

  char* ws = (char*)d_ws;
  float* y0  = (float*)ws;                           // 134217728 B
  float* h1  = (float*)(ws + 134217728);             // 134217728 B
  float* w1t = (float*)(ws + 268435456);             // 294912 B
  float* w2t = (float*)(ws + 268435456 + 294912);    // 262144 B

  prepack_w1<<<288, 256, 0, stream>>>(w1, w1t);
  prepack_w2<<<256, 256, 0, stream>>>(w2, w2t);
  ska_kernel<<<131072, 256, 0, stream>>>(x, dw, roi, out, y0);
  conv1_kernel<<<4096, 256, 0, stream>>>(y0, w1t, g1, b1, m1, v1, h1);
  conv2_kernel<<<4096, 256, 0, stream>>>(h1, w2t, g2, b2, m2, v2, out);
}

// Round 3
// 776.665 us; speedup vs baseline: 2.1282x; 1.5526x over previous
//
#include <hip/hip_runtime.h>
#include <hip/hip_bf16.h>

// FeatureInspector: ska (dynamic 3x3 per-group aggregation) -> *roi ->
// grouped conv3x3(G=8)+BN+ReLU -> conv1x1+BN -> out = ska + y
//
// R2: both convs on bf16 MFMA (16x16x32), fp32 accumulate.
//  conv1: implicit GEMM, 9 shifted K=32 (=ci of group) MFMAs; LDS x-tile
//         [px 18x18][ci 32 pad40] bf16; B-frags in registers from L2.
//  h1 stored bf16 channel-last [b][g][px][ci32] == conv2's A layout.
//  conv2: register GEMM M=64px/block, N=256, K=256; frags straight from
//         global (A L1-hit across waves, B 128KB L2-resident); no LDS.
//
// ws layout (bytes):
//   [0, 134217728)        y0 = ska*roi (fp32 planar)
//   [134217728, +67108864) h1t bf16 [b][g][hw][ci32]
//   [201326592, +147456)   w1b bf16 [g][khw][co][ci32]
//   [201474048, +131072)   w2b bf16 [co][ci256]

#define HW 16384
#define EPS 1e-5f

typedef __bf16 bf16x8 __attribute__((ext_vector_type(8)));
typedef short short8 __attribute__((ext_vector_type(8)));
typedef float floatx4 __attribute__((ext_vector_type(4)));

__device__ __forceinline__ unsigned short f2bf(float f) {
  unsigned u = __builtin_bit_cast(unsigned, f);
  unsigned r = u + 0x7FFFu + ((u >> 16) & 1u);
  return (unsigned short)(r >> 16);
}

__device__ __forceinline__ floatx4 mfma16(short8 a, short8 b, floatx4 c) {
  return __builtin_amdgcn_mfma_f32_16x16x32_bf16(
      __builtin_bit_cast(bf16x8, a), __builtin_bit_cast(bf16x8, b), c, 0, 0, 0);
}

__global__ __launch_bounds__(256) void prepack_w1b(const float* __restrict__ w1,
                                                   unsigned short* __restrict__ w1b) {
  int o = blockIdx.x * 256 + threadIdx.x;      // 73728 = 288 blocks
  int ci  = o & 31;
  int co  = (o >> 5) & 31;
  int khw = (o >> 10) % 9;
  int g   = (o >> 10) / 9;
  w1b[o] = f2bf(w1[((g * 32 + co) * 32 + ci) * 9 + khw]);
}

__global__ __launch_bounds__(256) void prepack_w2b(const float* __restrict__ w2,
                                                   unsigned short* __restrict__ w2b) {
  int o = blockIdx.x * 256 + threadIdx.x;      // 65536 = 256 blocks
  w2b[o] = f2bf(w2[o]);                        // [co][ci] both
}

// One thread per output element: ska -> d_out, ska*roi -> y0(ws)
__global__ __launch_bounds__(256) void ska_kernel(const float* __restrict__ x,
                                                  const float* __restrict__ dw,
                                                  const float* __restrict__ roi,
                                                  float* __restrict__ out,
                                                  float* __restrict__ y0) {
  int idx = blockIdx.x * 256 + threadIdx.x;
  int w = idx & 127;
  int h = (idx >> 7) & 127;
  int c = (idx >> 14) & 255;
  int b = idx >> 22;
  int g = c >> 5;

  const float* dwb = dw + ((size_t)(b * 8 + g) * 9) * HW + h * 128 + w;
  float s = 0.f;
#pragma unroll
  for (int kh = 0; kh < 3; ++kh) {
    int hh = h + kh - 1;
    if ((unsigned)hh >= 128u) continue;
#pragma unroll
    for (int kw = 0; kw < 3; ++kw) {
      int ww = w + kw - 1;
      if ((unsigned)ww >= 128u) continue;
      float xv = x[idx + (kh - 1) * 128 + (kw - 1)];
      float wv = dwb[(kh * 3 + kw) * HW];
      s += xv * wv;
    }
  }
  out[idx] = s;
  y0[idx]  = s * roi[b * HW + h * 128 + w];
}

// Grouped conv3x3 + BN1 + ReLU via MFMA.
// Block: 16x16 px tile of one (b,g); 4 waves; wave = 4 rows x 32 co.
// LDS: x-tile [18*18 px][ci stride 40] bf16 = 25920 B.
__global__ __launch_bounds__(256) void conv1_mfma(
    const float* __restrict__ y0, const unsigned short* __restrict__ w1b,
    const float* __restrict__ g1, const float* __restrict__ b1,
    const float* __restrict__ m1, const float* __restrict__ v1,
    unsigned short* __restrict__ h1t) {
  __shared__ unsigned short xt[324 * 40];

  int blk  = blockIdx.x;              // 4096 = 8b * 8g * 64 tiles
  int tile = blk & 63;
  int g    = (blk >> 6) & 7;
  int b    = blk >> 9;
  int h0   = (tile >> 3) * 16;
  int w0   = (tile & 7) * 16;
  int tid  = threadIdx.x;

  const float* xsrc = y0 + ((size_t)(b * 256 + g * 32)) * HW;
  for (int j = tid; j < 324 * 32; j += 256) {
    int ci = j >> 5;                  // j = ci*324+r would misorder; use r-major:
    // actually iterate r-major for coalesced global reads:
    // j = ci*324 + r  (ci slow) keeps 18-float runs contiguous in gw.
    ci = j / 324;
    int r  = j - ci * 324;
    int yy = r / 18, xx = r - yy * 18;
    int gh = h0 - 1 + yy, gw = w0 - 1 + xx;
    float v = 0.f;
    if ((unsigned)gh < 128u && (unsigned)gw < 128u)
      v = xsrc[ci * HW + gh * 128 + gw];
    xt[r * 40 + ci] = f2bf(v);
  }

  int wv = tid >> 6, lane = tid & 63, q = lane >> 4, n = lane & 15;

  // B-frags from global (L2-resident, 18 KB/group): [g][khw][co][ci32]
  short8 bf[9][2];
  const unsigned short* wgb = w1b + (size_t)g * 9 * 32 * 32;
#pragma unroll
  for (int khw = 0; khw < 9; ++khw) {
#pragma unroll
    for (int half = 0; half < 2; ++half)
      bf[khw][half] =
          *(const short8*)&wgb[(khw * 32 + half * 16 + n) * 32 + q * 8];
  }

  __syncthreads();

  floatx4 acc[4][2];
#pragma unroll
  for (int r = 0; r < 4; ++r)
#pragma unroll
    for (int half = 0; half < 2; ++half) acc[r][half] = (floatx4){0.f, 0.f, 0.f, 0.f};

#pragma unroll
  for (int r = 0; r < 4; ++r) {
    int row = wv * 4 + r;
#pragma unroll
    for (int khw = 0; khw < 9; ++khw) {
      int kh = khw / 3, kw = khw % 3;
      short8 a = *(const short8*)&xt[((row + kh) * 18 + kw + n) * 40 + q * 8];
      acc[r][0] = mfma16(a, bf[khw][0], acc[r][0]);
      acc[r][1] = mfma16(a, bf[khw][1], acc[r][1]);
    }
  }

  float inv[2], bias[2];
#pragma unroll
  for (int half = 0; half < 2; ++half) {
    int c = g * 32 + half * 16 + n;
    inv[half]  = g1[c] * rsqrtf(v1[c] + EPS);
    bias[half] = b1[c] - m1[c] * inv[half];
  }

  unsigned short* hb = h1t + ((size_t)(b * 8 + g) * HW) * 32;
#pragma unroll
  for (int r = 0; r < 4; ++r) {
    int h = h0 + wv * 4 + r;
#pragma unroll
    for (int half = 0; half < 2; ++half) {
#pragma unroll
      for (int reg = 0; reg < 4; ++reg) {
        int w = w0 + q * 4 + reg;
        float v = fmaxf(acc[r][half][reg] * inv[half] + bias[half], 0.f);
        hb[((size_t)(h * 128 + w)) * 32 + half * 16 + n] = f2bf(v);
      }
    }
  }
}

// 1x1 conv + BN2 + residual. Register GEMM: block = 64 px x 256 co of one b;
// wave = 64 px x 64 co. K = 256 (8 slabs of 32 = one group each). No LDS.
__global__ __launch_bounds__(256) void conv2_mfma(
    const unsigned short* __restrict__ h1t, const unsigned short* __restrict__ w2b,
    const float* __restrict__ g2, const float* __restrict__ b2,
    const float* __restrict__ m2, const float* __restrict__ v2,
    float* __restrict__ out) {
  int blk = blockIdx.x;               // 2048 = 8b * 256 px-tiles
  int b   = blk >> 8;
  int px0 = (blk & 255) * 64;
  int tid = threadIdx.x;
  int wv = tid >> 6, lane = tid & 63, q = lane >> 4, n = lane & 15;

  floatx4 acc[4][4];                  // [mt][nt]
#pragma unroll
  for (int mt = 0; mt < 4; ++mt)
#pragma unroll
    for (int nt = 0; nt < 4; ++nt) acc[mt][nt] = (floatx4){0.f, 0.f, 0.f, 0.f};

  for (int s = 0; s < 8; ++s) {       // K-slab = group s
    short8 a[4];
#pragma unroll
    for (int mt = 0; mt < 4; ++mt)
      a[mt] = *(const short8*)&h1t[((size_t)(b * 8 + s) * HW + px0 + mt * 16 + n) * 32 +
                                   q * 8];
#pragma unroll
    for (int nt = 0; nt < 4; ++nt) {
      int co = wv * 64 + nt * 16 + n;
      short8 bb = *(const short8*)&w2b[co * 256 + s * 32 + q * 8];
#pragma unroll
      for (int mt = 0; mt < 4; ++mt) acc[mt][nt] = mfma16(a[mt], bb, acc[mt][nt]);
    }
  }

#pragma unroll
  for (int nt = 0; nt < 4; ++nt) {
    int co = wv * 64 + nt * 16 + n;
    float inv  = g2[co] * rsqrtf(v2[co] + EPS);
    float bias = b2[co] - m2[co] * inv;
    float* ob = out + (size_t)(b * 256 + co) * HW;
#pragma unroll
    for (int mt = 0; mt < 4; ++mt) {
      int px = px0 + mt * 16 + q * 4;
      float4 sv = *(float4*)&ob[px];
      sv.x += acc[mt][nt][0] * inv + bias;
      sv.y += acc[mt][nt][1] * inv + bias;
      sv.z += acc[mt][nt][2] * inv + bias;
      sv.w += acc[mt][nt][3] * inv + bias;
      *(float4*)&ob[px] = sv;
    }
  }
}

extern "C" void kernel_launch(void* const* d_in, const int* in_sizes, int n_in,
                              void* d_out, int out_size, void* d_ws,
                              size_t ws_size, hipStream_t stream) {
  const float* x   = (const float*)d_in[0];
  const float* dw  = (const float*)d_in[1];
  const float* roi = (const float*)d_in[2];
  const float* w1  = (const float*)d_in[3];
  const float* g1  = (const float*)d_in[4];
  const float* b1  = (const float*)d_in[5];
  const float* m1  = (const float*)d_in[6];
  const float* v1  = (const float*)d_in[7];
  const float* w2  = (const float*)d_in[8];
  const float* g2  = (const float*)d_in[9];
  const float* b2  = (const float*)d_in[10];
  const float* m2  = (const float*)d_in[11];
  const float* v2  = (const float*)d_in[12];
  float* out = (float*)d_out;

  char* ws = (char*)d_ws;
  float*          y0  = (float*)ws;                          // 134217728 B
  unsigned short* h1t = (unsigned short*)(ws + 134217728);   // 67108864 B
  unsigned short* w1b = (unsigned short*)(ws + 201326592);   // 147456 B
  unsigned short* w2b = (unsigned short*)(ws + 201474048);   // 131072 B

  prepack_w1b<<<288, 256, 0, stream>>>(w1, w1b);
  prepack_w2b<<<256, 256, 0, stream>>>(w2, w2b);
  ska_kernel<<<131072, 256, 0, stream>>>(x, dw, roi, out, y0);
  conv1_mfma<<<4096, 256, 0, stream>>>(y0, w1b, g1, b1, m1, v1, h1t);
  conv2_mfma<<<2048, 256, 0, stream>>>(h1t, w2b, g2, b2, m2, v2, out);
}